// Round 5
// baseline (116.619 us; speedup 1.0000x reference)
//
#include <hip/hip_runtime.h>
#include <hip/hip_bf16.h>

#define T_SEQ 2048
#define EMB   128
#define H     16
#define BATCH 8
#define BQ    64          // query rows per phase-1 block
#define CHUNK 512         // keys per phase-1 chunk
#define MAXP  4           // max partials per row (2048/512)

// ---------------------------------------------------------------------------
// Kernel 1: QKV projection (fp32). 512 blocks x 256 thr; 32 rows/block.
// Thread (col 0..15, rg 0..15) computes q,k,v for rows {2rg, 2rg+1}.
// Only W staged in LDS (transposed, b128-readable); x read directly from
// global (16-way duplicate addresses served by L1; 16 KB row working set).
// Per 4-dim chunk: 2 global b128 + 3 LDS b128 feed 24 FMAs.
// ---------------------------------------------------------------------------
__global__ __launch_bounds__(256) void qkv_kernel(
    const float* __restrict__ x,
    const float* __restrict__ Wq,
    const float* __restrict__ Wk,
    const float* __restrict__ Wv,
    float* __restrict__ Q, float* __restrict__ K, float* __restrict__ V)
{
    __shared__ float Wt[3][16][132];    // 25.3 KB; stride 132 = 4 mod 32

    const int tid = threadIdx.x;
    const int r0  = blockIdx.x * 32;

    // Stage W transposed: 3*2048 floats; 6 float4 loads/thread.
    // Index into Wm with rem (offset WITHIN the matrix).
#pragma unroll
    for (int p = 0; p < 6; ++p) {
        const int idx4 = tid + p * 256;
        const int flat = idx4 * 4;
        const int m    = flat >> 11;
        const int rem  = flat & 2047;       // = d*16 + col within matrix m
        const int d    = rem >> 4;
        const int c0   = rem & 15;
        const float* Wm = (m == 0) ? Wq : (m == 1) ? Wk : Wv;
        float4 w = *reinterpret_cast<const float4*>(Wm + rem);
        Wt[m][c0    ][d] = w.x;
        Wt[m][c0 + 1][d] = w.y;
        Wt[m][c0 + 2][d] = w.z;
        Wt[m][c0 + 3][d] = w.w;
    }
    __syncthreads();

    const int col  = tid & 15;
    const int rg   = tid >> 4;              // 0..15
    const int rowA = r0 + 2 * rg;
    const int rowB = rowA + 1;
    const float* xA = x + (size_t)rowA * EMB;
    const float* xB = x + (size_t)rowB * EMB;

    float qa0 = 0.f, ka0 = 0.f, va0 = 0.f;
    float qa1 = 0.f, ka1 = 0.f, va1 = 0.f;
#pragma unroll
    for (int d0 = 0; d0 < 128; d0 += 4) {
        float4 a  = *reinterpret_cast<const float4*>(xA + d0);
        float4 bb = *reinterpret_cast<const float4*>(xB + d0);
        float4 wq = *reinterpret_cast<const float4*>(&Wt[0][col][d0]);
        float4 wk = *reinterpret_cast<const float4*>(&Wt[1][col][d0]);
        float4 wv = *reinterpret_cast<const float4*>(&Wt[2][col][d0]);
        qa0 += a.x*wq.x + a.y*wq.y + a.z*wq.z + a.w*wq.w;
        ka0 += a.x*wk.x + a.y*wk.y + a.z*wk.z + a.w*wk.w;
        va0 += a.x*wv.x + a.y*wv.y + a.z*wv.z + a.w*wv.w;
        qa1 += bb.x*wq.x + bb.y*wq.y + bb.z*wq.z + bb.w*wq.w;
        ka1 += bb.x*wk.x + bb.y*wk.y + bb.z*wk.z + bb.w*wk.w;
        va1 += bb.x*wv.x + bb.y*wv.y + bb.z*wv.z + bb.w*wv.w;
    }
    const size_t oA = (size_t)rowA * H + col;
    const size_t oB = (size_t)rowB * H + col;
    Q[oA] = qa0; K[oA] = ka0; V[oA] = va0;
    Q[oB] = qa1; K[oB] = ka1; V[oB] = va1;
}

// ---------------------------------------------------------------------------
// Kernel 2a: phase-1 flash attention, 2 Q-rows per thread.
// Grid: 640 blocks = 8 batches x 80 (qt,chunk) pairs (qt in 0..31, 64-row
// tiles; chunk count = qt/8+1). Block 256 thr = 8 key-lanes x 32 row-slots;
// each thread owns rows {i0+2s, i0+2s+1} -> every K/V b128 read from LDS
// feeds 2 rows of FMAs (halves LDS instr/FLOP vs round 4).
// Writes unnormalized partials (acc[16], m, l) stride-18 to ws.
// ---------------------------------------------------------------------------
__global__ __launch_bounds__(256) void attn_phase1(
    const float* __restrict__ Q, const float* __restrict__ K,
    const float* __restrict__ V, float* __restrict__ P2)
{
    __shared__ float Ks[64][20];
    __shared__ float Vs[64][20];

    const int tid = threadIdx.x;
    const int w   = blockIdx.x;
    const int b   = w / 80;
    const int r   = 79 - (w % 80);      // heavy (8-tile) blocks first
    int qt, cch;
    if (r < 8)       { qt = r;                 cch = 0; }
    else if (r < 24) { qt = 8  + (r - 8)  / 2; cch = (r - 8)  % 2; }
    else if (r < 48) { qt = 16 + (r - 24) / 3; cch = (r - 24) % 3; }
    else             { qt = 24 + (r - 48) / 4; cch = (r - 48) % 4; }

    const int i0     = qt * BQ;
    const int kbeg   = cch * CHUNK;
    const int kend   = min(i0 + BQ, kbeg + CHUNK);   // multiple of 64, <= 2048
    const int ntiles = (kend - kbeg) >> 6;

    const int c  = tid & 7;             // key lane 0..7
    const int s  = tid >> 3;            // row slot 0..31
    const int iA = i0 + 2 * s;
    const int iB = iA + 1;

    const float* Qb = Q + (size_t)b * T_SEQ * H;
    const float* Kb = K + (size_t)b * T_SEQ * H;
    const float* Vb = V + (size_t)b * T_SEQ * H;

    float qA[16], qB[16];
    {
        const float4* qp = reinterpret_cast<const float4*>(Qb + (size_t)iA * H);
        float4 a0 = qp[0], a1 = qp[1], a2 = qp[2], a3 = qp[3];
        qA[0]=a0.x; qA[1]=a0.y; qA[2]=a0.z; qA[3]=a0.w;
        qA[4]=a1.x; qA[5]=a1.y; qA[6]=a1.z; qA[7]=a1.w;
        qA[8]=a2.x; qA[9]=a2.y; qA[10]=a2.z; qA[11]=a2.w;
        qA[12]=a3.x; qA[13]=a3.y; qA[14]=a3.z; qA[15]=a3.w;
        const float4* qp2 = reinterpret_cast<const float4*>(Qb + (size_t)iB * H);
        float4 b0 = qp2[0], b1 = qp2[1], b2 = qp2[2], b3 = qp2[3];
        qB[0]=b0.x; qB[1]=b0.y; qB[2]=b0.z; qB[3]=b0.w;
        qB[4]=b1.x; qB[5]=b1.y; qB[6]=b1.z; qB[7]=b1.w;
        qB[8]=b2.x; qB[9]=b2.y; qB[10]=b2.z; qB[11]=b2.w;
        qB[12]=b3.x; qB[13]=b3.y; qB[14]=b3.z; qB[15]=b3.w;
    }

    float accA[16], accB[16];
#pragma unroll
    for (int d = 0; d < 16; ++d) { accA[d] = 0.f; accB[d] = 0.f; }
    float mA = -1e30f, lA = 0.f, mB = -1e30f, lB = 0.f;

    for (int kt = 0; kt < ntiles; ++kt) {
        const int j0 = kbeg + kt * 64;
        // Stage K,V tile: 1024 fp32 each; one float4 per thread (in-bounds:
        // kend <= 2048 always).
        {
            const int f  = tid * 4;
            const int jl = f >> 4;
            const int d0 = f & 15;
            float4 kv = *reinterpret_cast<const float4*>(Kb + (size_t)j0 * H + f);
            float4 vv = *reinterpret_cast<const float4*>(Vb + (size_t)j0 * H + f);
            *reinterpret_cast<float4*>(&Ks[jl][d0]) = kv;
            *reinterpret_cast<float4*>(&Vs[jl][d0]) = vv;
        }
        __syncthreads();

        float pA[8], pB[8];
        float tmaxA = -1e30f, tmaxB = -1e30f;
#pragma unroll
        for (int ii = 0; ii < 8; ++ii) {
            const int jl = ii * 8 + c;
            const float4* kp = reinterpret_cast<const float4*>(&Ks[jl][0]);
            float4 k0 = kp[0], k1 = kp[1], k2 = kp[2], k3 = kp[3];
            float sA = qA[0]*k0.x + qA[1]*k0.y + qA[2]*k0.z + qA[3]*k0.w
                     + qA[4]*k1.x + qA[5]*k1.y + qA[6]*k1.z + qA[7]*k1.w
                     + qA[8]*k2.x + qA[9]*k2.y + qA[10]*k2.z + qA[11]*k2.w
                     + qA[12]*k3.x + qA[13]*k3.y + qA[14]*k3.z + qA[15]*k3.w;
            float sB = qB[0]*k0.x + qB[1]*k0.y + qB[2]*k0.z + qB[3]*k0.w
                     + qB[4]*k1.x + qB[5]*k1.y + qB[6]*k1.z + qB[7]*k1.w
                     + qB[8]*k2.x + qB[9]*k2.y + qB[10]*k2.z + qB[11]*k2.w
                     + qB[12]*k3.x + qB[13]*k3.y + qB[14]*k3.z + qB[15]*k3.w;
            sA *= 0.25f;
            sB *= 0.25f;
            const int j = j0 + jl;
            if (j > iA) sA = -1e30f;        // causal mask (finite)
            if (j > iB) sB = -1e30f;
            pA[ii] = sA; tmaxA = fmaxf(tmaxA, sA);
            pB[ii] = sB; tmaxB = fmaxf(tmaxB, sB);
        }
        tmaxA = fmaxf(tmaxA, __shfl_xor(tmaxA, 1));
        tmaxA = fmaxf(tmaxA, __shfl_xor(tmaxA, 2));
        tmaxA = fmaxf(tmaxA, __shfl_xor(tmaxA, 4));
        tmaxB = fmaxf(tmaxB, __shfl_xor(tmaxB, 1));
        tmaxB = fmaxf(tmaxB, __shfl_xor(tmaxB, 2));
        tmaxB = fmaxf(tmaxB, __shfl_xor(tmaxB, 4));
        const float mnA = fmaxf(mA, tmaxA);
        const float mnB = fmaxf(mB, tmaxB);
        const float alA = __expf(mA - mnA);
        const float alB = __expf(mB - mnB);

        float psA = 0.f, psB = 0.f;
#pragma unroll
        for (int ii = 0; ii < 8; ++ii) {
            const float eA = __expf(pA[ii] - mnA);
            const float eB = __expf(pB[ii] - mnB);
            pA[ii] = eA; psA += eA;
            pB[ii] = eB; psB += eB;
        }
        psA += __shfl_xor(psA, 1); psA += __shfl_xor(psA, 2); psA += __shfl_xor(psA, 4);
        psB += __shfl_xor(psB, 1); psB += __shfl_xor(psB, 2); psB += __shfl_xor(psB, 4);
        lA = lA * alA + psA;  mA = mnA;
        lB = lB * alB + psB;  mB = mnB;

#pragma unroll
        for (int d = 0; d < 16; ++d) { accA[d] *= alA; accB[d] *= alB; }
#pragma unroll
        for (int ii = 0; ii < 8; ++ii) {
            const int jl = ii * 8 + c;
            const float eA = pA[ii];
            const float eB = pB[ii];
            const float4* vp = reinterpret_cast<const float4*>(&Vs[jl][0]);
            float4 v0 = vp[0], v1 = vp[1], v2 = vp[2], v3 = vp[3];
            accA[0]  += eA*v0.x; accA[1]  += eA*v0.y; accA[2]  += eA*v0.z; accA[3]  += eA*v0.w;
            accA[4]  += eA*v1.x; accA[5]  += eA*v1.y; accA[6]  += eA*v1.z; accA[7]  += eA*v1.w;
            accA[8]  += eA*v2.x; accA[9]  += eA*v2.y; accA[10] += eA*v2.z; accA[11] += eA*v2.w;
            accA[12] += eA*v3.x; accA[13] += eA*v3.y; accA[14] += eA*v3.z; accA[15] += eA*v3.w;
            accB[0]  += eB*v0.x; accB[1]  += eB*v0.y; accB[2]  += eB*v0.z; accB[3]  += eB*v0.w;
            accB[4]  += eB*v1.x; accB[5]  += eB*v1.y; accB[6]  += eB*v1.z; accB[7]  += eB*v1.w;
            accB[8]  += eB*v2.x; accB[9]  += eB*v2.y; accB[10] += eB*v2.z; accB[11] += eB*v2.w;
            accB[12] += eB*v3.x; accB[13] += eB*v3.y; accB[14] += eB*v3.z; accB[15] += eB*v3.w;
        }
        __syncthreads();
    }

    // Reduce acc across the 8 c-lanes; all lanes end with full row sums.
#pragma unroll
    for (int d = 0; d < 16; ++d) {
        float a = accA[d];
        a += __shfl_xor(a, 1); a += __shfl_xor(a, 2); a += __shfl_xor(a, 4);
        accA[d] = a;
        float bb = accB[d];
        bb += __shfl_xor(bb, 1); bb += __shfl_xor(bb, 2); bb += __shfl_xor(bb, 4);
        accB[d] = bb;
    }
    // Write unnormalized partials: [acc0..15, m, l] at slot (row, chunk).
    float* ppA = P2 + ((size_t)(b * T_SEQ + iA) * MAXP + cch) * 18;
    float* ppB = P2 + ((size_t)(b * T_SEQ + iB) * MAXP + cch) * 18;
    float2 rA; rA.x = accA[2*c]; rA.y = accA[2*c+1];
    float2 rB; rB.x = accB[2*c]; rB.y = accB[2*c+1];
    *reinterpret_cast<float2*>(ppA + 2*c) = rA;
    *reinterpret_cast<float2*>(ppB + 2*c) = rB;
    if (c == 0) { ppA[16] = mA; ppA[17] = lA; ppB[16] = mB; ppB[17] = lB; }
}

// ---------------------------------------------------------------------------
// Kernel 2b: combine partials. One thread per (row, dim).
// ---------------------------------------------------------------------------
__global__ __launch_bounds__(256) void attn_phase2(
    const float* __restrict__ P2, float* __restrict__ out)
{
    const int gid = blockIdx.x * 256 + threadIdx.x;   // 0..262143
    const int row = gid >> 4;
    const int d   = gid & 15;
    const int ib  = row & (T_SEQ - 1);
    const int nc  = (ib >> 9) + 1;                    // chunks this row used
    const float* base = P2 + (size_t)row * (MAXP * 18);

    float M = -1e30f;
    for (int p = 0; p < nc; ++p) M = fmaxf(M, base[p * 18 + 16]);
    float L = 0.f, o = 0.f;
    for (int p = 0; p < nc; ++p) {
        const float wgt = __expf(base[p * 18 + 16] - M);
        L += wgt * base[p * 18 + 17];
        o += wgt * base[p * 18 + d];
    }
    out[gid] = o / L;
}

// ---------------------------------------------------------------------------
extern "C" void kernel_launch(void* const* d_in, const int* in_sizes, int n_in,
                              void* d_out, int out_size, void* d_ws, size_t ws_size,
                              hipStream_t stream)
{
    const float* x  = (const float*)d_in[0];
    const float* Wq = (const float*)d_in[1];
    const float* Wk = (const float*)d_in[2];
    const float* Wv = (const float*)d_in[3];
    float* out = (float*)d_out;

    const size_t NQ = (size_t)BATCH * T_SEQ * H;    // 262144
    float* Qw = (float*)d_ws;
    float* Kw = Qw + NQ;
    float* Vw = Kw + NQ;
    float* P2 = Vw + NQ;                            // 16384*4*18 floats

    qkv_kernel<<<BATCH * T_SEQ / 32, 256, 0, stream>>>(x, Wq, Wk, Wv, Qw, Kw, Vw);
    attn_phase1<<<BATCH * 80, 256, 0, stream>>>(Qw, Kw, Vw, P2);
    attn_phase2<<<BATCH * T_SEQ * H / 256, 256, 0, stream>>>(P2, out);
}

// Round 6
// 90.286 us; speedup vs baseline: 1.2917x; 1.2917x over previous
//
#include <hip/hip_runtime.h>
#include <hip/hip_bf16.h>

#define T_SEQ 2048
#define EMB   128
#define H     16
#define BATCH 8
#define BQ    64          // query rows per phase-1 block (4 waves x 16 rows)

typedef short short8_t __attribute__((ext_vector_type(8)));  // 8 bf16 (4 VGPRs)
typedef float f32x4    __attribute__((ext_vector_type(4)));  // MFMA C/D frag

__device__ __forceinline__ unsigned short f2bf(float f) {
    __hip_bfloat16 h = __float2bfloat16(f);   // RNE
    return *reinterpret_cast<unsigned short*>(&h);
}

// ---------------------------------------------------------------------------
// Kernel 1: QKV projection. fp32 in; bf16 out: Qbf (pre-scaled by 0.25),
// Kbf row-major [b][key][dim]; Vt TRANSPOSED [b][dim][key] (bf16) so the PV
// MFMA A-fragment (V^T[dim][keys]) is a contiguous 16B load.
// Structure = round-5 (proven): W transposed in LDS, x direct from global.
// ---------------------------------------------------------------------------
__global__ __launch_bounds__(256) void qkv_kernel(
    const float* __restrict__ x,
    const float* __restrict__ Wq,
    const float* __restrict__ Wk,
    const float* __restrict__ Wv,
    unsigned short* __restrict__ Qbf,
    unsigned short* __restrict__ Kbf,
    unsigned short* __restrict__ Vt)
{
    __shared__ float Wt[3][16][132];    // 25.3 KB; stride 132 = 4 mod 32

    const int tid = threadIdx.x;
    const int r0  = blockIdx.x * 32;

#pragma unroll
    for (int p = 0; p < 6; ++p) {
        const int idx4 = tid + p * 256;
        const int flat = idx4 * 4;
        const int mm   = flat >> 11;
        const int rem  = flat & 2047;       // offset WITHIN matrix mm
        const int d    = rem >> 4;
        const int c0   = rem & 15;
        const float* Wm = (mm == 0) ? Wq : (mm == 1) ? Wk : Wv;
        float4 w = *reinterpret_cast<const float4*>(Wm + rem);
        Wt[mm][c0    ][d] = w.x;
        Wt[mm][c0 + 1][d] = w.y;
        Wt[mm][c0 + 2][d] = w.z;
        Wt[mm][c0 + 3][d] = w.w;
    }
    __syncthreads();

    const int col  = tid & 15;
    const int rg   = tid >> 4;
    const int rowA = r0 + 2 * rg;
    const int rowB = rowA + 1;
    const float* xA = x + (size_t)rowA * EMB;
    const float* xB = x + (size_t)rowB * EMB;

    float qa0 = 0.f, ka0 = 0.f, va0 = 0.f;
    float qa1 = 0.f, ka1 = 0.f, va1 = 0.f;
#pragma unroll
    for (int d0 = 0; d0 < 128; d0 += 4) {
        float4 a  = *reinterpret_cast<const float4*>(xA + d0);
        float4 bb = *reinterpret_cast<const float4*>(xB + d0);
        float4 wq = *reinterpret_cast<const float4*>(&Wt[0][col][d0]);
        float4 wk = *reinterpret_cast<const float4*>(&Wt[1][col][d0]);
        float4 wv = *reinterpret_cast<const float4*>(&Wt[2][col][d0]);
        qa0 += a.x*wq.x + a.y*wq.y + a.z*wq.z + a.w*wq.w;
        ka0 += a.x*wk.x + a.y*wk.y + a.z*wk.z + a.w*wk.w;
        va0 += a.x*wv.x + a.y*wv.y + a.z*wv.z + a.w*wv.w;
        qa1 += bb.x*wq.x + bb.y*wq.y + bb.z*wq.z + bb.w*wq.w;
        ka1 += bb.x*wk.x + bb.y*wk.y + bb.z*wk.z + bb.w*wk.w;
        va1 += bb.x*wv.x + bb.y*wv.y + bb.z*wv.z + bb.w*wv.w;
    }
    const int bA = rowA >> 11, iA = rowA & 2047;
    const int bB = rowB >> 11, iB = rowB & 2047;
    Qbf[(size_t)rowA * H + col] = f2bf(qa0 * 0.25f);   // fold 1/sqrt(16)
    Kbf[(size_t)rowA * H + col] = f2bf(ka0);
    Vt[((size_t)bA * H + col) * T_SEQ + iA] = f2bf(va0);
    Qbf[(size_t)rowB * H + col] = f2bf(qa1 * 0.25f);
    Kbf[(size_t)rowB * H + col] = f2bf(ka1);
    Vt[((size_t)bB * H + col) * T_SEQ + iB] = f2bf(va1);
}

// ---------------------------------------------------------------------------
// Kernel 2a: MFMA flash attention over one key chunk. Grid (32, maxp, 8);
// invalid (qt,cch) pairs exit immediately. 4 independent waves/block, wave w
// owns rows i0+16w..+15; NO barriers anywhere.
// Per 64-key tile: 4x mfma(S^T = K·Q^T, dims zero-padded to K=32), mask,
// online softmax (state in 4 lanes/row, 2 shuffles/reduce), P->LDS (bf16
// packed, per-wave buffer) to reach B-layout, 2x mfma(O^T += V^T·P^T, K=32).
// C/D layout [m89/m91]: col=lane&15, row=quad*4+reg.
// A layout [m120]: A[m=lane&15][k=quad*8+j]; B mirrors with n=lane&15.
// ---------------------------------------------------------------------------
__global__ __launch_bounds__(256) void attn_phase1(
    const unsigned short* __restrict__ Qbf,
    const unsigned short* __restrict__ Kbf,
    const unsigned short* __restrict__ Vt,
    float* __restrict__ P2, int cs, int maxp)
{
    __shared__ unsigned int Pbuf[4][32][17];   // per-wave [keypair][row], 8.7 KB

    const int qt   = blockIdx.x;
    const int cch  = blockIdx.y;
    const int b    = blockIdx.z;
    const int i0   = qt * BQ;
    const int kbeg = cch << cs;
    if (kbeg >= i0 + BQ) return;               // invalid chunk for this q-tile

    const int tid  = threadIdx.x;
    const int w    = tid >> 6;                 // wave 0..3
    const int lane = tid & 63;
    const int q    = lane >> 4;                // quad 0..3
    const int n    = lane & 15;                // row-in-tile / dim / key-in-subtile
    const int irow = i0 + w * 16 + n;          // this lane's Q row
    const int kend = min(kbeg + (1 << cs), i0 + w * 16 + 16);
    const int ntiles = (kend - kbeg + 63) >> 6;

    const unsigned short* Qp = Qbf + (size_t)b * T_SEQ * H;
    const unsigned short* Kp = Kbf + (size_t)b * T_SEQ * H;
    const unsigned short* Vp = Vt  + (size_t)b * H * T_SEQ;

    // Q fragment (B-operand): lane holds Q[row=n][dims q*8..+7]; dims 16..31 zero.
    short8_t qf = {0,0,0,0,0,0,0,0};
    if (q < 2)
        qf = *reinterpret_cast<const short8_t*>(Qp + (size_t)irow * H + q * 8);

    f32x4 acc = {0.f, 0.f, 0.f, 0.f};          // O^T frag: dims q*4+r, row n
    float m = -1e30f, l = 0.f;

    for (int kt = 0; kt < ntiles; ++kt) {
        const int j0 = kbeg + kt * 64;

        // Scores: S^T[key=q*4+r (in subtile s)][row=n]
        f32x4 S[4];
#pragma unroll
        for (int s = 0; s < 4; ++s) {
            short8_t kf = {0,0,0,0,0,0,0,0};   // A: K[key=n][dims q*8..+7]
            if (q < 2)
                kf = *reinterpret_cast<const short8_t*>(
                        Kp + (size_t)(j0 + s * 16 + n) * H + q * 8);
            f32x4 z = {0.f, 0.f, 0.f, 0.f};
            S[s] = __builtin_amdgcn_mfma_f32_16x16x32_bf16(kf, qf, z, 0, 0, 0);
        }

        // Causal mask + tile max (this lane holds 16 keys of row irow).
        float tm = -1e30f;
#pragma unroll
        for (int s = 0; s < 4; ++s) {
            const int kb = j0 + s * 16 + q * 4;
#pragma unroll
            for (int r = 0; r < 4; ++r) {
                float v = (kb + r <= irow) ? S[s][r] : -1e30f;
                S[s][r] = v;
                tm = fmaxf(tm, v);
            }
        }
        tm = fmaxf(tm, __shfl_xor(tm, 16));    // row state lives in 4 lanes
        tm = fmaxf(tm, __shfl_xor(tm, 32));
        const float mn    = fmaxf(m, tm);
        const float alpha = __expf(m - mn);
        m = mn;

        // exp, row-sum, and pack P^T into per-wave LDS (bf16, truncated).
        float ps = 0.f;
#pragma unroll
        for (int s = 0; s < 4; ++s) {
            float e0 = __expf(S[s][0] - mn);
            float e1 = __expf(S[s][1] - mn);
            float e2 = __expf(S[s][2] - mn);
            float e3 = __expf(S[s][3] - mn);
            ps += (e0 + e1) + (e2 + e3);
            unsigned int b0 = __builtin_bit_cast(unsigned int, e0);
            unsigned int b1 = __builtin_bit_cast(unsigned int, e1);
            unsigned int b2 = __builtin_bit_cast(unsigned int, e2);
            unsigned int b3 = __builtin_bit_cast(unsigned int, e3);
            Pbuf[w][s * 8 + q * 2 + 0][n] = (b1 & 0xffff0000u) | (b0 >> 16);
            Pbuf[w][s * 8 + q * 2 + 1][n] = (b3 & 0xffff0000u) | (b2 >> 16);
        }
        ps += __shfl_xor(ps, 16);
        ps += __shfl_xor(ps, 32);
        l = l * alpha + ps;
        acc[0] *= alpha; acc[1] *= alpha; acc[2] *= alpha; acc[3] *= alpha;

        // PV: O^T += V^T · P^T, two K=32 MFMAs.
#pragma unroll
        for (int h = 0; h < 2; ++h) {
            // A: V^T[dim=n][keys j0+h*32+q*8..+7] — contiguous in Vt.
            short8_t vf = *reinterpret_cast<const short8_t*>(
                    Vp + (size_t)n * T_SEQ + (j0 + h * 32 + q * 8));
            // B: P^T[key=q*8+j][row=n] from Pbuf keypairs.
            union { unsigned int u[4]; short8_t v; } pu;
            pu.u[0] = Pbuf[w][h * 16 + q * 4 + 0][n];
            pu.u[1] = Pbuf[w][h * 16 + q * 4 + 1][n];
            pu.u[2] = Pbuf[w][h * 16 + q * 4 + 2][n];
            pu.u[3] = Pbuf[w][h * 16 + q * 4 + 3][n];
            acc = __builtin_amdgcn_mfma_f32_16x16x32_bf16(vf, pu.v, acc, 0, 0, 0);
        }
    }

    // Unnormalized partial: lane writes dims q*4..+3 of row irow.
    float* pp = P2 + ((size_t)(b * T_SEQ + irow) * maxp + cch) * 18;
    float2 r01; r01.x = acc[0]; r01.y = acc[1];
    float2 r23; r23.x = acc[2]; r23.y = acc[3];
    *reinterpret_cast<float2*>(pp + q * 4)     = r01;
    *reinterpret_cast<float2*>(pp + q * 4 + 2) = r23;
    if (q == 0) { pp[16] = m; pp[17] = l; }
}

// ---------------------------------------------------------------------------
// Kernel 2b: combine partials. One thread per (row, dim).
// ---------------------------------------------------------------------------
__global__ __launch_bounds__(256) void attn_phase2(
    const float* __restrict__ P2, float* __restrict__ out, int cs, int maxp)
{
    const int gid = blockIdx.x * 256 + threadIdx.x;   // 0..262143
    const int row = gid >> 4;
    const int d   = gid & 15;
    const int ib  = row & (T_SEQ - 1);
    const int nc  = (ib >> cs) + 1;                   // chunks this row used
    const float* base = P2 + (size_t)row * maxp * 18;

    float M = -1e30f;
    for (int p = 0; p < nc; ++p) M = fmaxf(M, base[p * 18 + 16]);
    float L = 0.f, o = 0.f;
    for (int p = 0; p < nc; ++p) {
        const float wgt = __expf(base[p * 18 + 16] - M);
        L += wgt * base[p * 18 + 17];
        o += wgt * base[p * 18 + d];
    }
    out[gid] = o / L;
}

// ---------------------------------------------------------------------------
extern "C" void kernel_launch(void* const* d_in, const int* in_sizes, int n_in,
                              void* d_out, int out_size, void* d_ws, size_t ws_size,
                              hipStream_t stream)
{
    const float* x  = (const float*)d_in[0];
    const float* Wq = (const float*)d_in[1];
    const float* Wk = (const float*)d_in[2];
    const float* Wv = (const float*)d_in[3];
    float* out = (float*)d_out;

    const size_t NE = (size_t)BATCH * T_SEQ * H;      // 262144 elems per buf
    unsigned short* Qbf = (unsigned short*)d_ws;
    unsigned short* Kbf = Qbf + NE;
    unsigned short* Vt  = Kbf + NE;
    float* P2 = (float*)(Vt + NE);                    // after 1.5 MB of bf16

    // CHUNK=256 (cs=8, maxp=8) needs ~10.9 MB; fall back to CHUNK=512
    // (6.2 MB, proven available) if ws is small.
    const size_t need8 = 3 * NE * 2 + (size_t)BATCH * T_SEQ * 8 * 18 * 4;
    int cs, maxp;
    if (ws_size >= need8) { cs = 8; maxp = 8; }
    else                  { cs = 9; maxp = 4; }

    qkv_kernel<<<BATCH * T_SEQ / 32, 256, 0, stream>>>(x, Wq, Wk, Wv, Qbf, Kbf, Vt);
    attn_phase1<<<dim3(T_SEQ / BQ, maxp, BATCH), 256, 0, stream>>>(
        Qbf, Kbf, Vt, P2, cs, maxp);
    attn_phase2<<<(int)(NE / 256), 256, 0, stream>>>(P2, out, cs, maxp);
}

// Round 8
// 89.787 us; speedup vs baseline: 1.2988x; 1.0056x over previous
//
#include <hip/hip_runtime.h>
#include <hip/hip_bf16.h>

#define T_SEQ 2048
#define EMB   128
#define H     16
#define BATCH 8
#define BQ    64          // query rows per phase-1 block (4 waves x 16 rows)
// Q pre-scale: 1/sqrt(16) * log2(e)  -> scores come out in log2 domain
#define QSCALE 0.360673760222241f

// exp2 via the clang builtin that lowers straight to v_exp_f32 (D = 2^S0).
// NOTE: __exp2f clashes with a glibc math.h macro in this compile mode (r7).
#define EXP2F(x) __builtin_amdgcn_exp2f(x)

typedef short short8_t __attribute__((ext_vector_type(8)));  // 8 bf16 (4 VGPRs)
typedef float f32x4    __attribute__((ext_vector_type(4)));  // MFMA C/D frag

__device__ __forceinline__ unsigned short f2bf(float f) {
    __hip_bfloat16 h = __float2bfloat16(f);   // RNE
    return *reinterpret_cast<unsigned short*>(&h);
}

// ---------------------------------------------------------------------------
// Kernel 1: QKV projection via MFMA. 256 blocks x 4 waves; wave w computes
// rows blockIdx*64 + w*16 .. +15 for all three projections.
// A-frag: x[row=n][dims t*32+q*8..+7] fp32->bf16 inline.
// B-frag: Wt[m][col=n][dims ...] staged bf16 in LDS.
// D (C-layout [m89]): lane(q,n) holds proj[row=q*4+r][col=n] -> Q/K row-major
// scalar stores + Vt[b][dim][row] packed 4-row 8B store.
// Q is pre-scaled by QSCALE (log2-domain softmax downstream).
// ---------------------------------------------------------------------------
__global__ __launch_bounds__(256) void qkv_kernel(
    const float* __restrict__ x,
    const float* __restrict__ Wq,
    const float* __restrict__ Wk,
    const float* __restrict__ Wv,
    unsigned short* __restrict__ Qbf,
    unsigned short* __restrict__ Kbf,
    unsigned short* __restrict__ Vt)
{
    __shared__ unsigned short Wt[3][16][136];   // 13 KB, bf16, [m][col][dim]

    const int tid = threadIdx.x;
    // Stage W: 3*2048 fp32, coalesced float4 loads, bf16-convert, transpose.
#pragma unroll
    for (int p = 0; p < 6; ++p) {
        const int idx4 = tid + p * 256;
        const int flat = idx4 * 4;
        const int mm   = flat >> 11;
        const int rem  = flat & 2047;           // d*16 + col within matrix mm
        const int d    = rem >> 4;
        const int c0   = rem & 15;
        const float* Wm = (mm == 0) ? Wq : (mm == 1) ? Wk : Wv;
        float4 w = *reinterpret_cast<const float4*>(Wm + rem);
        Wt[mm][c0    ][d] = f2bf(w.x);
        Wt[mm][c0 + 1][d] = f2bf(w.y);
        Wt[mm][c0 + 2][d] = f2bf(w.z);
        Wt[mm][c0 + 3][d] = f2bf(w.w);
    }
    __syncthreads();

    const int w4   = tid >> 6;                  // wave 0..3
    const int lane = tid & 63;
    const int q    = lane >> 4;                 // quad
    const int n    = lane & 15;
    const int row0 = blockIdx.x * 64 + w4 * 16; // wave's row base (batch-safe)
    const float* xr = x + (size_t)(row0 + n) * EMB;

    f32x4 aq = {0,0,0,0}, ak = {0,0,0,0}, av = {0,0,0,0};
#pragma unroll
    for (int t = 0; t < 4; ++t) {
        const int k0 = t * 32 + q * 8;
        float4 xa = *reinterpret_cast<const float4*>(xr + k0);
        float4 xb = *reinterpret_cast<const float4*>(xr + k0 + 4);
        union { unsigned short s[8]; short8_t v; } xf;
        xf.s[0]=f2bf(xa.x); xf.s[1]=f2bf(xa.y); xf.s[2]=f2bf(xa.z); xf.s[3]=f2bf(xa.w);
        xf.s[4]=f2bf(xb.x); xf.s[5]=f2bf(xb.y); xf.s[6]=f2bf(xb.z); xf.s[7]=f2bf(xb.w);
        short8_t wqf = *reinterpret_cast<const short8_t*>(&Wt[0][n][k0]);
        short8_t wkf = *reinterpret_cast<const short8_t*>(&Wt[1][n][k0]);
        short8_t wvf = *reinterpret_cast<const short8_t*>(&Wt[2][n][k0]);
        aq = __builtin_amdgcn_mfma_f32_16x16x32_bf16(xf.v, wqf, aq, 0, 0, 0);
        ak = __builtin_amdgcn_mfma_f32_16x16x32_bf16(xf.v, wkf, ak, 0, 0, 0);
        av = __builtin_amdgcn_mfma_f32_16x16x32_bf16(xf.v, wvf, av, 0, 0, 0);
    }

    const int grow = row0 + q * 4;              // global row of r=0
    const int b    = grow >> 11;
    const int ib0  = grow & 2047;
#pragma unroll
    for (int r = 0; r < 4; ++r) {
        Qbf[(size_t)(grow + r) * H + n] = f2bf(aq[r] * QSCALE);
        Kbf[(size_t)(grow + r) * H + n] = f2bf(ak[r]);
    }
    union { unsigned short s[4]; unsigned long long u; } vp;
    vp.s[0]=f2bf(av[0]); vp.s[1]=f2bf(av[1]); vp.s[2]=f2bf(av[2]); vp.s[3]=f2bf(av[3]);
    *reinterpret_cast<unsigned long long*>(
        Vt + ((size_t)b * H + n) * T_SEQ + ib0) = vp.u;
}

// ---------------------------------------------------------------------------
// Kernel 2a: MFMA flash attention over one key chunk (log2-domain softmax).
// Grid (32, maxp, 8); invalid (qt,cch) exit. 4 independent waves/block,
// NO barriers. Per 64-key tile: 4x mfma(S^T=K·Q^T), uniform-skip causal
// mask, online softmax via exp2 (state in 4 lanes/row), P->per-wave LDS
// (bf16) to B-layout, 2x mfma(O^T += V^T·P^T).
// ---------------------------------------------------------------------------
__global__ __launch_bounds__(256) void attn_phase1(
    const unsigned short* __restrict__ Qbf,
    const unsigned short* __restrict__ Kbf,
    const unsigned short* __restrict__ Vt,
    float* __restrict__ P2, int cs, int maxp)
{
    __shared__ unsigned int Pbuf[4][32][17];   // per-wave [keypair][row], 8.7 KB

    const int qt   = blockIdx.x;
    const int cch  = blockIdx.y;
    const int b    = blockIdx.z;
    const int i0   = qt * BQ;
    const int kbeg = cch << cs;
    if (kbeg >= i0 + BQ) return;               // invalid chunk for this q-tile

    const int tid  = threadIdx.x;
    const int w    = tid >> 6;                 // wave 0..3
    const int lane = tid & 63;
    const int q    = lane >> 4;
    const int n    = lane & 15;
    const int wrow0 = i0 + w * 16;             // wave's min row
    const int irow  = wrow0 + n;
    const int kend  = min(kbeg + (1 << cs), wrow0 + 16);
    const int ntiles = (kend - kbeg + 63) >> 6;

    const unsigned short* Qp = Qbf + (size_t)b * T_SEQ * H;
    const unsigned short* Kp = Kbf + (size_t)b * T_SEQ * H;
    const unsigned short* Vp = Vt  + (size_t)b * H * T_SEQ;

    short8_t qf = {0,0,0,0,0,0,0,0};
    if (q < 2)
        qf = *reinterpret_cast<const short8_t*>(Qp + (size_t)irow * H + q * 8);

    f32x4 acc = {0.f, 0.f, 0.f, 0.f};
    float m = -1e30f, l = 0.f;

    for (int kt = 0; kt < ntiles; ++kt) {
        const int j0 = kbeg + kt * 64;

        // Scores: S^T[key][row], log2 domain (Q pre-scaled).
        f32x4 S[4];
#pragma unroll
        for (int s = 0; s < 4; ++s) {
            short8_t kf = {0,0,0,0,0,0,0,0};
            if (q < 2)
                kf = *reinterpret_cast<const short8_t*>(
                        Kp + (size_t)(j0 + s * 16 + n) * H + q * 8);
            f32x4 z = {0.f, 0.f, 0.f, 0.f};
            S[s] = __builtin_amdgcn_mfma_f32_16x16x32_bf16(kf, qf, z, 0, 0, 0);
        }

        // V fragments early: hides L2 latency under the softmax VALU work.
        short8_t vf0 = *reinterpret_cast<const short8_t*>(
                Vp + (size_t)n * T_SEQ + (j0 + q * 8));
        short8_t vf1 = *reinterpret_cast<const short8_t*>(
                Vp + (size_t)n * T_SEQ + (j0 + 32 + q * 8));

        // Causal mask only when the tile straddles the diagonal (wave-uniform).
        float tm = -1e30f;
        if (j0 + 63 > wrow0) {
#pragma unroll
            for (int s = 0; s < 4; ++s) {
                const int kb = j0 + s * 16 + q * 4;
#pragma unroll
                for (int r = 0; r < 4; ++r) {
                    float v = (kb + r <= irow) ? S[s][r] : -1e30f;
                    S[s][r] = v;
                    tm = fmaxf(tm, v);
                }
            }
        } else {
#pragma unroll
            for (int s = 0; s < 4; ++s) {
                tm = fmaxf(tm, fmaxf(fmaxf(S[s][0], S[s][1]),
                                     fmaxf(S[s][2], S[s][3])));
            }
        }
        tm = fmaxf(tm, __shfl_xor(tm, 16));
        tm = fmaxf(tm, __shfl_xor(tm, 32));
        const float mn    = fmaxf(m, tm);
        const float alpha = EXP2F(m - mn);
        m = mn;

        float ps = 0.f;
#pragma unroll
        for (int s = 0; s < 4; ++s) {
            float e0 = EXP2F(S[s][0] - mn);
            float e1 = EXP2F(S[s][1] - mn);
            float e2 = EXP2F(S[s][2] - mn);
            float e3 = EXP2F(S[s][3] - mn);
            ps += (e0 + e1) + (e2 + e3);
            unsigned int b0 = __builtin_bit_cast(unsigned int, e0);
            unsigned int b1 = __builtin_bit_cast(unsigned int, e1);
            unsigned int b2 = __builtin_bit_cast(unsigned int, e2);
            unsigned int b3 = __builtin_bit_cast(unsigned int, e3);
            Pbuf[w][s * 8 + q * 2 + 0][n] = (b1 & 0xffff0000u) | (b0 >> 16);
            Pbuf[w][s * 8 + q * 2 + 1][n] = (b3 & 0xffff0000u) | (b2 >> 16);
        }
        ps += __shfl_xor(ps, 16);
        ps += __shfl_xor(ps, 32);
        l = l * alpha + ps;
        acc[0] *= alpha; acc[1] *= alpha; acc[2] *= alpha; acc[3] *= alpha;

        // PV: O^T += V^T · P^T
        {
            union { unsigned int u[4]; short8_t v; } pu;
            pu.u[0] = Pbuf[w][q * 4 + 0][n];
            pu.u[1] = Pbuf[w][q * 4 + 1][n];
            pu.u[2] = Pbuf[w][q * 4 + 2][n];
            pu.u[3] = Pbuf[w][q * 4 + 3][n];
            acc = __builtin_amdgcn_mfma_f32_16x16x32_bf16(vf0, pu.v, acc, 0, 0, 0);
            pu.u[0] = Pbuf[w][16 + q * 4 + 0][n];
            pu.u[1] = Pbuf[w][16 + q * 4 + 1][n];
            pu.u[2] = Pbuf[w][16 + q * 4 + 2][n];
            pu.u[3] = Pbuf[w][16 + q * 4 + 3][n];
            acc = __builtin_amdgcn_mfma_f32_16x16x32_bf16(vf1, pu.v, acc, 0, 0, 0);
        }
    }

    float* pp = P2 + ((size_t)(b * T_SEQ + irow) * maxp + cch) * 18;
    float2 r01; r01.x = acc[0]; r01.y = acc[1];
    float2 r23; r23.x = acc[2]; r23.y = acc[3];
    *reinterpret_cast<float2*>(pp + q * 4)     = r01;
    *reinterpret_cast<float2*>(pp + q * 4 + 2) = r23;
    if (q == 0) { pp[16] = m; pp[17] = l; }
}

// ---------------------------------------------------------------------------
// Kernel 2b: combine partials (log2 domain). One thread per (row, dim).
// ---------------------------------------------------------------------------
__global__ __launch_bounds__(256) void attn_phase2(
    const float* __restrict__ P2, float* __restrict__ out, int cs, int maxp)
{
    const int gid = blockIdx.x * 256 + threadIdx.x;
    const int row = gid >> 4;
    const int d   = gid & 15;
    const int ib  = row & (T_SEQ - 1);
    const int nc  = (ib >> cs) + 1;
    const float* base = P2 + (size_t)row * maxp * 18;

    float M = -1e30f;
    for (int p = 0; p < nc; ++p) M = fmaxf(M, base[p * 18 + 16]);
    float L = 0.f, o = 0.f;
    for (int p = 0; p < nc; ++p) {
        const float wgt = EXP2F(base[p * 18 + 16] - M);
        L += wgt * base[p * 18 + 17];
        o += wgt * base[p * 18 + d];
    }
    out[gid] = o / L;
}

// ---------------------------------------------------------------------------
extern "C" void kernel_launch(void* const* d_in, const int* in_sizes, int n_in,
                              void* d_out, int out_size, void* d_ws, size_t ws_size,
                              hipStream_t stream)
{
    const float* x  = (const float*)d_in[0];
    const float* Wq = (const float*)d_in[1];
    const float* Wk = (const float*)d_in[2];
    const float* Wv = (const float*)d_in[3];
    float* out = (float*)d_out;

    const size_t NE = (size_t)BATCH * T_SEQ * H;      // 262144 elems per buf
    unsigned short* Qbf = (unsigned short*)d_ws;
    unsigned short* Kbf = Qbf + NE;
    unsigned short* Vt  = Kbf + NE;
    float* P2 = (float*)(Vt + NE);

    const size_t need8 = 3 * NE * 2 + (size_t)BATCH * T_SEQ * 8 * 18 * 4;
    int cs, maxp;
    if (ws_size >= need8) { cs = 8; maxp = 8; }
    else                  { cs = 9; maxp = 4; }

    qkv_kernel<<<BATCH * T_SEQ / 64, 256, 0, stream>>>(x, Wq, Wk, Wv, Qbf, Kbf, Vt);
    attn_phase1<<<dim3(T_SEQ / BQ, maxp, BATCH), 256, 0, stream>>>(
        Qbf, Kbf, Vt, P2, cs, maxp);
    attn_phase2<<<(int)(NE / 256), 256, 0, stream>>>(P2, out, cs, maxp);
}